// Round 5
// baseline (924.966 us; speedup 1.0000x reference)
//
#include <hip/hip_runtime.h>
#include <hip/hip_bf16.h>

// TransformerLayer (Swin shifted-window attention + MLP), MI355X gfx950.
// I/O is FP32 (per reference; round-4 evidence: NaN vanished after fp32->bf16
// input conversion, residual 10.84 error matched bf16-written/fp32-read skew).
// Compute: bf16 MFMA (m97 structure: 128x128 tile, BK=32, 16x16x32 bf16 MFMA,
// global_load_lds width=16), fp32 accumulate, fp32 scores+mask, fp32 residual.
//
// Phases / 64 MiB ws regions (A/B/C = 16 MiB each, D = weights+P):
//  0. cvt weights->D, target->A(tgt16)
//  1. vw  = QKVgemm(tgt16,Wv)->B ; vwT = transpose->C ; kw = QKVgemm(tgt16,Wk)->B
//  2. cvt source->A(src16) ; qw = QKVgemm(src16,Wq)->d_out[0,16.8M)
//  3. 8x batch: score(qw,kw)->S=d_out[16.8,33.5M) fp32 ; softmax S->P(D+4M) ;
//     PV(P,vwT)->msg[b] (overwrites dead qw[b] in d_out)
//  4. msg_mm = gemm(msg,Wm)->B ; LN1->C(msg_ln)
//  5. 4x slab: hid = gemm_concat_gelu(src16|msg_ln, W1)->d_out ; mlp=gemm(hid,W2)->B
//  6. LN2(mlp)*g+b + source(fp32) -> d_out fp32

using bf16 = __hip_bfloat16;
typedef __attribute__((ext_vector_type(8))) short short8;
typedef __attribute__((ext_vector_type(4))) float f32x4;

__device__ __forceinline__ float bf2f(unsigned short b) {
    return __uint_as_float(((unsigned)b) << 16);
}
__device__ __forceinline__ unsigned short f2bf(float f) {
    unsigned u = __float_as_uint(f);
    unsigned r = (u + 0x7FFFu + ((u >> 16) & 1u)) >> 16;
    return (unsigned short)r;
}
__device__ __forceinline__ void cp16(const void* g, void* l) {
    __builtin_amdgcn_global_load_lds((const __attribute__((address_space(1))) void*)g,
                                     (__attribute__((address_space(3))) void*)l,
                                     16, 0, 0);
}

constexpr int MODE_PLAIN = 0;
constexpr int MODE_QKV   = 1;  // store bf16 at roll(-16)+window-permuted row
constexpr int MODE_SCORE = 2;  // store fp32 acc*scale + mask[win&3] (mask fp32)
constexpr int MODE_PV    = 3;  // store bf16 at de-windowed + inverse-roll row
constexpr int MODE_GELU  = 4;  // exact gelu then bf16 store

// C[M,N] = A[M,K] @ B[N,K]^T ; all operands bf16, acc fp32.
template<int MODE, bool CONCAT>
__global__ __launch_bounds__(256)
void gemm_bt(const bf16* __restrict__ A, const bf16* __restrict__ A2,
             const bf16* __restrict__ Bm, void* __restrict__ C,
             const float* __restrict__ mask,
             int K, int ldc, long sAz, long sBz, long sCz,
             int wbase, float scale)
{
    __shared__ __align__(16) bf16 As[128 * 32];
    __shared__ __align__(16) bf16 Bs[128 * 32];

    const int z = blockIdx.z;
    A  += (long)z * sAz;
    Bm += (long)z * sBz;

    const int tid  = threadIdx.x;
    const int wave = tid >> 6, lane = tid & 63;
    const int wm = wave >> 1, wn = wave & 1;
    const int quad = lane >> 4, lrow = lane & 15;
    const int m0 = blockIdx.x * 128, n0 = blockIdx.y * 128;

    f32x4 acc[4][4];
#pragma unroll
    for (int i = 0; i < 4; i++)
#pragma unroll
        for (int j = 0; j < 4; j++) acc[i][j] = (f32x4){0.f, 0.f, 0.f, 0.f};

    for (int k0 = 0; k0 < K; k0 += 32) {
#pragma unroll
        for (int inst = 0; inst < 2; ++inst) {
            const int chunk = wave * 2 + inst;        // 0..7, 16 rows each
            const int u   = chunk * 64 + lane;        // 16B-unit index 0..511
            const int row = u >> 2;                   // 0..127
            const int kk  = (u & 3) << 3;             // 0/8/16/24
            const bf16* ga;
            if (CONCAT) {
                ga = (k0 < 256) ? (A  + (long)(m0 + row) * 256 + (k0 + kk))
                                : (A2 + (long)(m0 + row) * 256 + (k0 - 256 + kk));
            } else {
                ga = A + (long)(m0 + row) * K + (k0 + kk);
            }
            cp16(ga, As + chunk * 512);
            const bf16* gb = Bm + (long)(n0 + row) * K + (k0 + kk);
            cp16(gb, Bs + chunk * 512);
        }
        __syncthreads();

        short8 af[4], bfv[4];
#pragma unroll
        for (int i = 0; i < 4; i++) {
            af[i]  = *(const short8*)(As + (wm * 64 + i * 16 + lrow) * 32 + quad * 8);
            bfv[i] = *(const short8*)(Bs + (wn * 64 + i * 16 + lrow) * 32 + quad * 8);
        }
#pragma unroll
        for (int i = 0; i < 4; i++)
#pragma unroll
            for (int j = 0; j < 4; j++)
                acc[i][j] = __builtin_amdgcn_mfma_f32_16x16x32_bf16(
                    af[i], bfv[j], acc[i][j], 0, 0, 0);
        __syncthreads();
    }

    // epilogue: C/D layout col = lane&15, row = quad*4 + reg (m89/m91 verified)
    unsigned short* outb = (unsigned short*)C;
    if (MODE == MODE_SCORE) {
        float* outf = (float*)C + (long)z * sCz;
        const int wi = (wbase + z) & 3;
        const float* mrow = mask + (((long)wi) << 20);
#pragma unroll
        for (int i = 0; i < 4; i++)
#pragma unroll
            for (int j = 0; j < 4; j++)
#pragma unroll
                for (int r = 0; r < 4; r++) {
                    const int gm = m0 + wm * 64 + i * 16 + quad * 4 + r;
                    const int gn = n0 + wn * 64 + j * 16 + lrow;
                    outf[((long)gm << 10) + gn] =
                        acc[i][j][r] * scale + mrow[((long)gm << 10) + gn];
                }
    } else if (MODE == MODE_PV) {
        const int win = wbase + z;
        const int batch = win >> 2;
        const int s1 = (win >> 1) & 1, s2 = win & 1;
#pragma unroll
        for (int i = 0; i < 4; i++)
#pragma unroll
            for (int j = 0; j < 4; j++)
#pragma unroll
                for (int r = 0; r < 4; r++) {
                    const int gm = m0 + wm * 64 + i * 16 + quad * 4 + r; // local l
                    const int gn = n0 + wn * 64 + j * 16 + lrow;
                    const int r5 = gm >> 5, c5 = gm & 31;
                    const int ii = ((s1 << 5) + r5 + 16) & 63;   // inverse roll
                    const int jj = ((s2 << 5) + c5 + 16) & 63;
                    const long mr = (long)batch * 4096 + ii * 64 + jj;
                    outb[mr * 256 + gn] = f2bf(acc[i][j][r]);
                }
    } else if (MODE == MODE_QKV) {
#pragma unroll
        for (int i = 0; i < 4; i++)
#pragma unroll
            for (int j = 0; j < 4; j++)
#pragma unroll
                for (int r = 0; r < 4; r++) {
                    const int gm = m0 + wm * 64 + i * 16 + quad * 4 + r;
                    const int gn = n0 + wn * 64 + j * 16 + lrow;
                    const int batch = gm >> 12, pos = gm & 4095;
                    const int ii = pos >> 6, jj = pos & 63;
                    const int ri = (ii + 48) & 63, rj = (jj + 48) & 63; // roll(-16)
                    const long prow =
                        ((long)((batch << 2) + ((ri >> 5) << 1) + (rj >> 5)) << 10)
                        + ((ri & 31) << 5) + (rj & 31);
                    outb[prow * 256 + gn] = f2bf(acc[i][j][r]);
                }
    } else {
#pragma unroll
        for (int i = 0; i < 4; i++)
#pragma unroll
            for (int j = 0; j < 4; j++)
#pragma unroll
                for (int r = 0; r < 4; r++) {
                    const int gm = m0 + wm * 64 + i * 16 + quad * 4 + r;
                    const int gn = n0 + wn * 64 + j * 16 + lrow;
                    float v = acc[i][j][r];
                    if (MODE == MODE_GELU)
                        v = 0.5f * v * (1.f + erff(v * 0.7071067811865476f));
                    outb[(long)gm * ldc + gn] = f2bf(v);
                }
    }
}

// fp32 -> bf16 conversion, n4 = n/4 float4 groups
__global__ __launch_bounds__(256)
void cvt_k(const float* __restrict__ s, unsigned short* __restrict__ d, long n4)
{
    for (long i = (long)blockIdx.x * 256 + threadIdx.x; i < n4;
         i += (long)gridDim.x * 256) {
        const float4 v = ((const float4*)s)[i];
        ushort4 o;
        o.x = f2bf(v.x); o.y = f2bf(v.y); o.z = f2bf(v.z); o.w = f2bf(v.w);
        ((ushort4*)d)[i] = o;
    }
}

// vwT[win][c][s] = vw[win][s][c], 64x64 LDS tiles
__global__ __launch_bounds__(256)
void transpose_vw(const bf16* __restrict__ vw, bf16* __restrict__ vwT)
{
    __shared__ bf16 t[64][65];
    const int win = blockIdx.z;
    const int s0 = blockIdx.x * 64, c0 = blockIdx.y * 64;
    const bf16* src = vw  + ((long)win << 18);
    bf16*       dst = vwT + ((long)win << 18);
    const int tid = threadIdx.x;
#pragma unroll
    for (int ii = 0; ii < 16; ++ii) {
        const int lin = ii * 256 + tid;
        const int r = lin >> 6, c = lin & 63;
        t[r][c] = src[(long)(s0 + r) * 256 + c0 + c];
    }
    __syncthreads();
#pragma unroll
    for (int ii = 0; ii < 16; ++ii) {
        const int lin = ii * 256 + tid;
        const int r = lin >> 6, c = lin & 63;
        dst[(long)(c0 + r) * 1024 + s0 + c] = t[c][r];
    }
}

// one 1024-wide fp32 row per block -> softmax -> bf16
__global__ __launch_bounds__(256)
void softmax_k(const float* __restrict__ S, bf16* __restrict__ P)
{
    const long row = blockIdx.x;
    const int tid = threadIdx.x, wave = tid >> 6, lane = tid & 63;
    const float4 x = ((const float4*)(S + (row << 10)))[tid];
    __shared__ float sm[4], ss[4];

    float mx = fmaxf(fmaxf(x.x, x.y), fmaxf(x.z, x.w));
#pragma unroll
    for (int o = 1; o < 64; o <<= 1) mx = fmaxf(mx, __shfl_xor(mx, o, 64));
    if (lane == 0) sm[wave] = mx;
    __syncthreads();
    mx = fmaxf(fmaxf(sm[0], sm[1]), fmaxf(sm[2], sm[3]));

    const float e0 = __expf(x.x - mx), e1 = __expf(x.y - mx);
    const float e2 = __expf(x.z - mx), e3 = __expf(x.w - mx);
    float s = e0 + e1 + e2 + e3;
#pragma unroll
    for (int o = 1; o < 64; o <<= 1) s += __shfl_xor(s, o, 64);
    if (lane == 0) ss[wave] = s;
    __syncthreads();
    const float inv = 1.f / (ss[0] + ss[1] + ss[2] + ss[3]);

    ushort4 o4;
    o4.x = f2bf(e0 * inv); o4.y = f2bf(e1 * inv);
    o4.z = f2bf(e2 * inv); o4.w = f2bf(e3 * inv);
    ((ushort4*)((unsigned short*)P + (row << 10)))[tid] = o4;
}

// LN1: bf16 in -> bf16 out, fp32 gamma/beta, no residual. One 256-ch row/wave.
__global__ __launch_bounds__(256)
void ln1_k(const bf16* __restrict__ x, const float* __restrict__ g,
           const float* __restrict__ be, bf16* __restrict__ out)
{
    const int wave = threadIdx.x >> 6, lane = threadIdx.x & 63;
    const long row = (long)blockIdx.x * 4 + wave;
    const ushort4 u = ((const ushort4*)((const unsigned short*)x + (row << 8)))[lane];
    const float v0 = bf2f(u.x), v1 = bf2f(u.y), v2 = bf2f(u.z), v3 = bf2f(u.w);
    float s = v0 + v1 + v2 + v3;
    float q = v0 * v0 + v1 * v1 + v2 * v2 + v3 * v3;
#pragma unroll
    for (int o = 1; o < 64; o <<= 1) { s += __shfl_xor(s, o, 64); q += __shfl_xor(q, o, 64); }
    const float mean = s * 0.00390625f;
    const float var  = q * 0.00390625f - mean * mean;
    const float inv  = rsqrtf(fmaxf(var, 0.f) + 1e-5f);
    const float4 gg = ((const float4*)g)[lane];
    const float4 bb = ((const float4*)be)[lane];
    ushort4 o4;
    o4.x = f2bf((v0 - mean) * inv * gg.x + bb.x);
    o4.y = f2bf((v1 - mean) * inv * gg.y + bb.y);
    o4.z = f2bf((v2 - mean) * inv * gg.z + bb.z);
    o4.w = f2bf((v3 - mean) * inv * gg.w + bb.w);
    ((ushort4*)((unsigned short*)out + (row << 8)))[lane] = o4;
}

// LN2 + residual: bf16 in, fp32 gamma/beta/residual, fp32 out.
__global__ __launch_bounds__(256)
void ln2_k(const bf16* __restrict__ x, const float* __restrict__ g,
           const float* __restrict__ be, const float* __restrict__ res,
           float* __restrict__ out)
{
    const int wave = threadIdx.x >> 6, lane = threadIdx.x & 63;
    const long row = (long)blockIdx.x * 4 + wave;
    const ushort4 u = ((const ushort4*)((const unsigned short*)x + (row << 8)))[lane];
    const float v0 = bf2f(u.x), v1 = bf2f(u.y), v2 = bf2f(u.z), v3 = bf2f(u.w);
    float s = v0 + v1 + v2 + v3;
    float q = v0 * v0 + v1 * v1 + v2 * v2 + v3 * v3;
#pragma unroll
    for (int o = 1; o < 64; o <<= 1) { s += __shfl_xor(s, o, 64); q += __shfl_xor(q, o, 64); }
    const float mean = s * 0.00390625f;
    const float var  = q * 0.00390625f - mean * mean;
    const float inv  = rsqrtf(fmaxf(var, 0.f) + 1e-5f);
    const float4 gg = ((const float4*)g)[lane];
    const float4 bb = ((const float4*)be)[lane];
    const float4 rr = ((const float4*)(res + (row << 8)))[lane];
    float4 o4;
    o4.x = (v0 - mean) * inv * gg.x + bb.x + rr.x;
    o4.y = (v1 - mean) * inv * gg.y + bb.y + rr.y;
    o4.z = (v2 - mean) * inv * gg.z + bb.z + rr.z;
    o4.w = (v3 - mean) * inv * gg.w + bb.w + rr.w;
    ((float4*)(out + (row << 8)))[lane] = o4;
}

extern "C" void kernel_launch(void* const* d_in, const int* in_sizes, int n_in,
                              void* d_out, int out_size, void* d_ws, size_t ws_size,
                              hipStream_t stream)
{
    // ALL float tensors are fp32 (reference dtypes; confirmed round 4)
    const float* source = (const float*)d_in[0];
    const float* target = (const float*)d_in[1];
    const float* mask   = (const float*)d_in[2];
    const float* Wq = (const float*)d_in[3];
    const float* Wk = (const float*)d_in[4];
    const float* Wv = (const float*)d_in[5];
    const float* Wm = (const float*)d_in[6];
    const float* ln1g = (const float*)d_in[7];
    const float* ln1b = (const float*)d_in[8];
    const float* W1 = (const float*)d_in[9];
    const float* W2 = (const float*)d_in[10];
    const float* ln2g = (const float*)d_in[11];
    const float* ln2b = (const float*)d_in[12];
    float* out = (float*)d_out;

    char* ws = (char*)d_ws;
    const size_t MB = 1ull << 20;
    const size_t KB = 1024;

    // 64 MiB ws regions
    bf16* RA = (bf16*)(ws +  0 * MB);   // tgt16 -> src16
    bf16* RB = (bf16*)(ws + 16 * MB);   // vw -> kw -> msg_mm -> mlp_out
    bf16* RC = (bf16*)(ws + 32 * MB);   // vwT -> msg_ln
    char* D  = ws + 48 * MB;
    bf16* Wq16 = (bf16*)(D + 0 * KB);    // 128 KB
    bf16* Wk16 = (bf16*)(D + 128 * KB);
    bf16* Wv16 = (bf16*)(D + 256 * KB);
    bf16* Wm16 = (bf16*)(D + 384 * KB);
    bf16* W116 = (bf16*)(D + 512 * KB);  // 2 MiB
    bf16* W216 = (bf16*)(D + 2560 * KB); // 1 MiB
    bf16* Pb   = (bf16*)(D + 4 * MB);    // 8 MiB (4 windows bf16)
    // d_out (33.55 MB fp32) as phased scratch:
    bf16*  qw  = (bf16*)d_out;                  // [0, 16.78 MB)
    float* S   = (float*)d_out + 4194304;       // [16.78, 33.55 MB)
    bf16*  msg = qw;                            // overwrites dead qw[b]
    bf16*  hid = (bf16*)d_out;                  // MLP slab scratch (33.55 MB)

    const float scale = 0.0625f;  // 1/sqrt(256)

    // 0) convert weights + target to bf16
    cvt_k<<<64,   256, 0, stream>>>(Wq, (unsigned short*)Wq16, 16384);
    cvt_k<<<64,   256, 0, stream>>>(Wk, (unsigned short*)Wk16, 16384);
    cvt_k<<<64,   256, 0, stream>>>(Wv, (unsigned short*)Wv16, 16384);
    cvt_k<<<64,   256, 0, stream>>>(Wm, (unsigned short*)Wm16, 16384);
    cvt_k<<<1024, 256, 0, stream>>>(W1, (unsigned short*)W116, 262144);
    cvt_k<<<512,  256, 0, stream>>>(W2, (unsigned short*)W216, 131072);
    cvt_k<<<8192, 256, 0, stream>>>(target, (unsigned short*)RA, 2097152);

    // 1) V/K projections (windowed store), V transpose
    gemm_bt<MODE_QKV, false><<<dim3(256, 2, 1), 256, 0, stream>>>(
        RA, nullptr, Wv16, RB, nullptr, 256, 256, 0, 0, 0, 0, 0.f);
    transpose_vw<<<dim3(16, 4, 32), 256, 0, stream>>>(RB, RC);
    gemm_bt<MODE_QKV, false><<<dim3(256, 2, 1), 256, 0, stream>>>(
        RA, nullptr, Wk16, RB, nullptr, 256, 256, 0, 0, 0, 0, 0.f);
    // RA (tgt16) now dead -> src16
    cvt_k<<<8192, 256, 0, stream>>>(source, (unsigned short*)RA, 2097152);
    gemm_bt<MODE_QKV, false><<<dim3(256, 2, 1), 256, 0, stream>>>(
        RA, nullptr, Wq16, qw, nullptr, 256, 256, 0, 0, 0, 0, 0.f);

    // 2) attention, 8 chunks of 4 windows (= batch b); kw=RB, vwT=RC
    for (int b = 0; b < 8; ++b) {
        const long wo = (long)b * 4 * 262144;
        gemm_bt<MODE_SCORE, false><<<dim3(8, 8, 4), 256, 0, stream>>>(
            qw + wo, nullptr, RB + wo, S, mask,
            256, 1024, 262144, 262144, 1048576, b * 4, scale);
        softmax_k<<<4096, 256, 0, stream>>>(S, Pb);
        gemm_bt<MODE_PV, false><<<dim3(8, 2, 4), 256, 0, stream>>>(
            Pb, nullptr, RC + wo, msg, nullptr,
            1024, 256, 1048576, 262144, 0, b * 4, 0.f);
    }

    // 3) msg @ Wm^T -> RB ; LN1 -> RC
    gemm_bt<MODE_PLAIN, false><<<dim3(256, 2, 1), 256, 0, stream>>>(
        msg, nullptr, Wm16, RB, nullptr, 256, 256, 0, 0, 0, 0, 0.f);
    ln1_k<<<8192, 256, 0, stream>>>(RB, ln1g, ln1b, RC);

    // 4) MLP, 4 slabs of 8192 rows: hid in d_out, mlp out in RB
    for (int sl = 0; sl < 4; ++sl) {
        const long ro = (long)sl * 8192 * 256;
        gemm_bt<MODE_GELU, true><<<dim3(64, 16, 1), 256, 0, stream>>>(
            RA + ro, RC + ro, W116, hid, nullptr, 512, 2048, 0, 0, 0, 0, 0.f);
        gemm_bt<MODE_PLAIN, false><<<dim3(64, 2, 1), 256, 0, stream>>>(
            hid, nullptr, W216, RB + ro, nullptr, 2048, 256, 0, 0, 0, 0, 0.f);
    }

    // 5) LN2 + fp32 residual -> d_out (fp32), fully overwrites scratch
    ln2_k<<<8192, 256, 0, stream>>>(RB, ln2g, ln2b, source, out);
}

// Round 6
// 732.323 us; speedup vs baseline: 1.2631x; 1.2631x over previous
//
#include <hip/hip_runtime.h>
#include <hip/hip_bf16.h>

// TransformerLayer (Swin shifted-window attention + MLP), fp32 I/O, MI355X.
// R6: fused score+softmax kernel (no S materialization), PV consolidated to
// z=16, merged weight-cvt, 22 dispatches total.
// Phases:
//  0. cvtw weights->D ; cvt target->d_out.lo ; cvt source->d_out.hi
//  1. vw=QKV(tgt,Wv)->RB ; vwT=transpose->RC ; kw=QKV(tgt,Wk)->RB ; qw=QKV(src,Wq)->RA
//  2. 2x half (16 win): attn_sm(qw,kw,mask)->P=d_out(33.5MB bf16) ;
//     PV(P,vwT)->msg (overwrites dead qw half in RA)
//  3. msg@Wm^T->RB ; LN1->RC(msg_ln) ; cvt source->RA(src16)
//  4. 4x slab: MLP1(src16|msg_ln,W1,gelu)->hid=d_out ; MLP2(hid,W2)->RB
//  5. LN2(RB)+source(fp32) -> d_out fp32

using bf16 = __hip_bfloat16;
typedef __attribute__((ext_vector_type(8))) short short8;
typedef __attribute__((ext_vector_type(4))) float f32x4;

__device__ __forceinline__ float bf2f(unsigned short b) {
    return __uint_as_float(((unsigned)b) << 16);
}
__device__ __forceinline__ unsigned short f2bf(float f) {
    unsigned u = __float_as_uint(f);
    unsigned r = (u + 0x7FFFu + ((u >> 16) & 1u)) >> 16;
    return (unsigned short)r;
}
__device__ __forceinline__ void cp16(const void* g, void* l) {
    __builtin_amdgcn_global_load_lds((const __attribute__((address_space(1))) void*)g,
                                     (__attribute__((address_space(3))) void*)l,
                                     16, 0, 0);
}

constexpr int MODE_PLAIN = 0;
constexpr int MODE_QKV   = 1;  // store bf16 at roll(-16)+window-permuted row
constexpr int MODE_PV    = 2;  // store bf16 at de-windowed + inverse-roll row
constexpr int MODE_GELU  = 3;  // exact gelu then bf16 store

// C[M,N] = A[M,K] @ B[N,K]^T ; bf16 operands, fp32 acc. m97 structure.
template<int MODE, bool CONCAT>
__global__ __launch_bounds__(256)
void gemm_bt(const bf16* __restrict__ A, const bf16* __restrict__ A2,
             const bf16* __restrict__ Bm, void* __restrict__ C,
             int K, int ldc, long sAz, long sBz, int wbase)
{
    __shared__ __align__(16) bf16 As[128 * 32];
    __shared__ __align__(16) bf16 Bs[128 * 32];

    const int z = blockIdx.z;
    A  += (long)z * sAz;
    Bm += (long)z * sBz;

    const int tid  = threadIdx.x;
    const int wave = tid >> 6, lane = tid & 63;
    const int wm = wave >> 1, wn = wave & 1;
    const int quad = lane >> 4, lrow = lane & 15;
    const int m0 = blockIdx.x * 128, n0 = blockIdx.y * 128;

    f32x4 acc[4][4];
#pragma unroll
    for (int i = 0; i < 4; i++)
#pragma unroll
        for (int j = 0; j < 4; j++) acc[i][j] = (f32x4){0.f, 0.f, 0.f, 0.f};

    for (int k0 = 0; k0 < K; k0 += 32) {
#pragma unroll
        for (int inst = 0; inst < 2; ++inst) {
            const int chunk = wave * 2 + inst;
            const int u   = chunk * 64 + lane;
            const int row = u >> 2;
            const int kk  = (u & 3) << 3;
            const bf16* ga;
            if (CONCAT) {
                ga = (k0 < 256) ? (A  + (long)(m0 + row) * 256 + (k0 + kk))
                                : (A2 + (long)(m0 + row) * 256 + (k0 - 256 + kk));
            } else {
                ga = A + (long)(m0 + row) * K + (k0 + kk);
            }
            cp16(ga, As + chunk * 512);
            const bf16* gb = Bm + (long)(n0 + row) * K + (k0 + kk);
            cp16(gb, Bs + chunk * 512);
        }
        __syncthreads();

        short8 af[4], bfv[4];
#pragma unroll
        for (int i = 0; i < 4; i++) {
            af[i]  = *(const short8*)(As + (wm * 64 + i * 16 + lrow) * 32 + quad * 8);
            bfv[i] = *(const short8*)(Bs + (wn * 64 + i * 16 + lrow) * 32 + quad * 8);
        }
#pragma unroll
        for (int i = 0; i < 4; i++)
#pragma unroll
            for (int j = 0; j < 4; j++)
                acc[i][j] = __builtin_amdgcn_mfma_f32_16x16x32_bf16(
                    af[i], bfv[j], acc[i][j], 0, 0, 0);
        __syncthreads();
    }

    // C/D layout: col = lane&15, row = quad*4 + reg (m89/m91 verified)
    unsigned short* outb = (unsigned short*)C;
    if (MODE == MODE_PV) {
        const int win = wbase + z;
        const int batch = win >> 2;
        const int s1 = (win >> 1) & 1, s2 = win & 1;
#pragma unroll
        for (int i = 0; i < 4; i++)
#pragma unroll
            for (int j = 0; j < 4; j++)
#pragma unroll
                for (int r = 0; r < 4; r++) {
                    const int gm = m0 + wm * 64 + i * 16 + quad * 4 + r;
                    const int gn = n0 + wn * 64 + j * 16 + lrow;
                    const int r5 = gm >> 5, c5 = gm & 31;
                    const int ii = ((s1 << 5) + r5 + 16) & 63;   // inverse roll
                    const int jj = ((s2 << 5) + c5 + 16) & 63;
                    const long mr = (long)batch * 4096 + ii * 64 + jj;
                    outb[mr * 256 + gn] = f2bf(acc[i][j][r]);
                }
    } else if (MODE == MODE_QKV) {
#pragma unroll
        for (int i = 0; i < 4; i++)
#pragma unroll
            for (int j = 0; j < 4; j++)
#pragma unroll
                for (int r = 0; r < 4; r++) {
                    const int gm = m0 + wm * 64 + i * 16 + quad * 4 + r;
                    const int gn = n0 + wn * 64 + j * 16 + lrow;
                    const int batch = gm >> 12, pos = gm & 4095;
                    const int ii = pos >> 6, jj = pos & 63;
                    const int ri = (ii + 48) & 63, rj = (jj + 48) & 63; // roll(-16)
                    const long prow =
                        ((long)((batch << 2) + ((ri >> 5) << 1) + (rj >> 5)) << 10)
                        + ((ri & 31) << 5) + (rj & 31);
                    outb[prow * 256 + gn] = f2bf(acc[i][j][r]);
                }
    } else {
#pragma unroll
        for (int i = 0; i < 4; i++)
#pragma unroll
            for (int j = 0; j < 4; j++)
#pragma unroll
                for (int r = 0; r < 4; r++) {
                    const int gm = m0 + wm * 64 + i * 16 + quad * 4 + r;
                    const int gn = n0 + wn * 64 + j * 16 + lrow;
                    float v = acc[i][j][r];
                    if (MODE == MODE_GELU)
                        v = 0.5f * v * (1.f + erff(v * 0.7071067811865476f));
                    outb[(long)gm * ldc + gn] = f2bf(v);
                }
    }
}

// Fused score+softmax: one block = 32 Q-rows x full 1024 K-cols of one window.
// P[row,col] = softmax_col(QK^T * scale + mask[win&3]). grid (32, nwin).
__global__ __launch_bounds__(256)
void attn_sm(const bf16* __restrict__ Q, const bf16* __restrict__ Kw,
             const float* __restrict__ mask, bf16* __restrict__ P, int wbase)
{
    __shared__ __align__(16) bf16 Ks[1024 * 32];   // 64 KB
    __shared__ __align__(16) bf16 Qs[32 * 32];     // 2 KB
    __shared__ float redm[2][2][16], redl[2][2][16];

    const int win = blockIdx.y;
    const long wo = (long)win << 18;               // *262144
    const bf16* Qp = Q + wo;
    const bf16* Kp = Kw + wo;
    unsigned short* Pp = (unsigned short*)P + ((long)win << 20);
    const float* mk = mask + (((long)((wbase + win) & 3)) << 20);

    const int tid = threadIdx.x;
    const int wave = tid >> 6, lane = tid & 63;
    const int wm = wave >> 1, wn = wave & 1;
    const int quad = lane >> 4, lrow = lane & 15;
    const int m0 = blockIdx.x * 32;

    f32x4 acc[32];
#pragma unroll
    for (int t = 0; t < 32; t++) acc[t] = (f32x4){0.f, 0.f, 0.f, 0.f};

    for (int k0 = 0; k0 < 256; k0 += 32) {
        if (wave < 2) {  // Q-tile 32x32: 128 16B-units, waves 0-1
            const int u = wave * 64 + lane;
            const int row = u >> 2, kk = (u & 3) << 3;
            cp16(Qp + (long)(m0 + row) * 256 + k0 + kk, Qs + u * 8);
        }
#pragma unroll
        for (int i = 0; i < 16; ++i) {   // K-tile 1024x32: 4096 units
            const int c = wave * 16 + i;              // 0..63
            const int u = c * 64 + lane;
            const int row = u >> 2, kk = (u & 3) << 3;
            cp16(Kp + (long)row * 256 + k0 + kk, Ks + c * 512 + lane * 8);
        }
        __syncthreads();
        const short8 af = *(const short8*)(Qs + (wm * 16 + lrow) * 32 + quad * 8);
#pragma unroll
        for (int t = 0; t < 32; ++t) {
            const short8 bfv = *(const short8*)(Ks + (wn * 512 + t * 16 + lrow) * 32 + quad * 8);
            acc[t] = __builtin_amdgcn_mfma_f32_16x16x32_bf16(af, bfv, acc[t], 0, 0, 0);
        }
        __syncthreads();
    }

    // lane holds rows (m0 + wm*16 + quad*4 + r), cols (wn*512 + t*16 + lrow)
    const int rowb = m0 + wm * 16 + quad * 4;
    for (int t = 0; t < 32; ++t) {
        const int gc = wn * 512 + t * 16 + lrow;
#pragma unroll
        for (int r = 0; r < 4; ++r)
            acc[t][r] = acc[t][r] * 0.0625f + mk[(long)(rowb + r) << 10 | gc];
    }

    float m_[4], fac[4];
#pragma unroll
    for (int r = 0; r < 4; ++r) {
        float mx = -3.4e38f;
        for (int t = 0; t < 32; ++t) mx = fmaxf(mx, acc[t][r]);
#pragma unroll
        for (int o = 1; o < 16; o <<= 1) mx = fmaxf(mx, __shfl_xor(mx, o, 64));
        m_[r] = mx;
        float s = 0.f;
        for (int t = 0; t < 32; ++t) { const float e = __expf(acc[t][r] - mx); acc[t][r] = e; s += e; }
#pragma unroll
        for (int o = 1; o < 16; o <<= 1) s += __shfl_xor(s, o, 64);
        fac[r] = s;   // temp: wave-half sum
    }
    if (lrow == 0) {
#pragma unroll
        for (int r = 0; r < 4; ++r) {
            redm[wm][wn][quad * 4 + r] = m_[r];
            redl[wm][wn][quad * 4 + r] = fac[r];
        }
    }
    __syncthreads();
#pragma unroll
    for (int r = 0; r < 4; ++r) {
        const int ri = quad * 4 + r;
        const float ma = redm[wm][0][ri], mb = redm[wm][1][ri];
        const float M = fmaxf(ma, mb);
        const float L = redl[wm][0][ri] * __expf(ma - M) + redl[wm][1][ri] * __expf(mb - M);
        fac[r] = __expf(m_[r] - M) / L;
    }
    for (int t = 0; t < 32; ++t) {
        const int gc = wn * 512 + t * 16 + lrow;
#pragma unroll
        for (int r = 0; r < 4; ++r)
            Pp[(long)(rowb + r) << 10 | gc] = f2bf(acc[t][r] * fac[r]);
    }
}

// merged weight conversion: 6 segments by blockIdx.y, into D (ushort)
__global__ __launch_bounds__(256)
void cvtw_k(const float* __restrict__ w0, const float* __restrict__ w1,
            const float* __restrict__ w2, const float* __restrict__ w3,
            const float* __restrict__ w4, const float* __restrict__ w5,
            unsigned short* __restrict__ d)
{
    const float* s; long n4, off4;
    switch (blockIdx.y) {
    case 0:  s = w0; n4 = 16384;  off4 = 0;      break;
    case 1:  s = w1; n4 = 16384;  off4 = 16384;  break;
    case 2:  s = w2; n4 = 16384;  off4 = 32768;  break;
    case 3:  s = w3; n4 = 16384;  off4 = 49152;  break;
    case 4:  s = w4; n4 = 262144; off4 = 65536;  break;
    default: s = w5; n4 = 131072; off4 = 327680; break;
    }
    ushort4* dst = (ushort4*)d + off4;
    for (long i = (long)blockIdx.x * 256 + threadIdx.x; i < n4;
         i += (long)gridDim.x * 256) {
        const float4 v = ((const float4*)s)[i];
        ushort4 o;
        o.x = f2bf(v.x); o.y = f2bf(v.y); o.z = f2bf(v.z); o.w = f2bf(v.w);
        dst[i] = o;
    }
}

__global__ __launch_bounds__(256)
void cvt_k(const float* __restrict__ s, unsigned short* __restrict__ d, long n4)
{
    for (long i = (long)blockIdx.x * 256 + threadIdx.x; i < n4;
         i += (long)gridDim.x * 256) {
        const float4 v = ((const float4*)s)[i];
        ushort4 o;
        o.x = f2bf(v.x); o.y = f2bf(v.y); o.z = f2bf(v.z); o.w = f2bf(v.w);
        ((ushort4*)d)[i] = o;
    }
}

// vwT[win][c][s] = vw[win][s][c], 64x64 LDS tiles
__global__ __launch_bounds__(256)
void transpose_vw(const bf16* __restrict__ vw, bf16* __restrict__ vwT)
{
    __shared__ bf16 t[64][65];
    const int win = blockIdx.z;
    const int s0 = blockIdx.x * 64, c0 = blockIdx.y * 64;
    const bf16* src = vw  + ((long)win << 18);
    bf16*       dst = vwT + ((long)win << 18);
    const int tid = threadIdx.x;
#pragma unroll
    for (int ii = 0; ii < 16; ++ii) {
        const int lin = ii * 256 + tid;
        const int r = lin >> 6, c = lin & 63;
        t[r][c] = src[(long)(s0 + r) * 256 + c0 + c];
    }
    __syncthreads();
#pragma unroll
    for (int ii = 0; ii < 16; ++ii) {
        const int lin = ii * 256 + tid;
        const int r = lin >> 6, c = lin & 63;
        dst[(long)(c0 + r) * 1024 + s0 + c] = t[c][r];
    }
}

// LN1: bf16 in -> bf16 out, fp32 gamma/beta. One 256-ch row per wave.
__global__ __launch_bounds__(256)
void ln1_k(const bf16* __restrict__ x, const float* __restrict__ g,
           const float* __restrict__ be, bf16* __restrict__ out)
{
    const int wave = threadIdx.x >> 6, lane = threadIdx.x & 63;
    const long row = (long)blockIdx.x * 4 + wave;
    const ushort4 u = ((const ushort4*)((const unsigned short*)x + (row << 8)))[lane];
    const float v0 = bf2f(u.x), v1 = bf2f(u.y), v2 = bf2f(u.z), v3 = bf2f(u.w);
    float s = v0 + v1 + v2 + v3;
    float q = v0 * v0 + v1 * v1 + v2 * v2 + v3 * v3;
#pragma unroll
    for (int o = 1; o < 64; o <<= 1) { s += __shfl_xor(s, o, 64); q += __shfl_xor(q, o, 64); }
    const float mean = s * 0.00390625f;
    const float var  = q * 0.00390625f - mean * mean;
    const float inv  = rsqrtf(fmaxf(var, 0.f) + 1e-5f);
    const float4 gg = ((const float4*)g)[lane];
    const float4 bb = ((const float4*)be)[lane];
    ushort4 o4;
    o4.x = f2bf((v0 - mean) * inv * gg.x + bb.x);
    o4.y = f2bf((v1 - mean) * inv * gg.y + bb.y);
    o4.z = f2bf((v2 - mean) * inv * gg.z + bb.z);
    o4.w = f2bf((v3 - mean) * inv * gg.w + bb.w);
    ((ushort4*)((unsigned short*)out + (row << 8)))[lane] = o4;
}

// LN2 + residual: bf16 in, fp32 gamma/beta/residual, fp32 out.
__global__ __launch_bounds__(256)
void ln2_k(const bf16* __restrict__ x, const float* __restrict__ g,
           const float* __restrict__ be, const float* __restrict__ res,
           float* __restrict__ out)
{
    const int wave = threadIdx.x >> 6, lane = threadIdx.x & 63;
    const long row = (long)blockIdx.x * 4 + wave;
    const ushort4 u = ((const ushort4*)((const unsigned short*)x + (row << 8)))[lane];
    const float v0 = bf2f(u.x), v1 = bf2f(u.y), v2 = bf2f(u.z), v3 = bf2f(u.w);
    float s = v0 + v1 + v2 + v3;
    float q = v0 * v0 + v1 * v1 + v2 * v2 + v3 * v3;
#pragma unroll
    for (int o = 1; o < 64; o <<= 1) { s += __shfl_xor(s, o, 64); q += __shfl_xor(q, o, 64); }
    const float mean = s * 0.00390625f;
    const float var  = q * 0.00390625f - mean * mean;
    const float inv  = rsqrtf(fmaxf(var, 0.f) + 1e-5f);
    const float4 gg = ((const float4*)g)[lane];
    const float4 bb = ((const float4*)be)[lane];
    const float4 rr = ((const float4*)(res + (row << 8)))[lane];
    float4 o4;
    o4.x = (v0 - mean) * inv * gg.x + bb.x + rr.x;
    o4.y = (v1 - mean) * inv * gg.y + bb.y + rr.y;
    o4.z = (v2 - mean) * inv * gg.z + bb.z + rr.z;
    o4.w = (v3 - mean) * inv * gg.w + bb.w + rr.w;
    ((float4*)(out + (row << 8)))[lane] = o4;
}

extern "C" void kernel_launch(void* const* d_in, const int* in_sizes, int n_in,
                              void* d_out, int out_size, void* d_ws, size_t ws_size,
                              hipStream_t stream)
{
    const float* source = (const float*)d_in[0];
    const float* target = (const float*)d_in[1];
    const float* mask   = (const float*)d_in[2];
    const float* Wq = (const float*)d_in[3];
    const float* Wk = (const float*)d_in[4];
    const float* Wv = (const float*)d_in[5];
    const float* Wm = (const float*)d_in[6];
    const float* ln1g = (const float*)d_in[7];
    const float* ln1b = (const float*)d_in[8];
    const float* W1 = (const float*)d_in[9];
    const float* W2 = (const float*)d_in[10];
    const float* ln2g = (const float*)d_in[11];
    const float* ln2b = (const float*)d_in[12];
    float* out = (float*)d_out;

    char* ws = (char*)d_ws;
    const size_t MB = 1ull << 20;

    bf16* RA = (bf16*)(ws +  0 * MB);   // qw -> msg -> src16
    bf16* RB = (bf16*)(ws + 16 * MB);   // vw -> kw -> msg_mm -> mlp_out
    bf16* RC = (bf16*)(ws + 32 * MB);   // vwT -> msg_ln
    unsigned short* D = (unsigned short*)(ws + 48 * MB);  // bf16 weights, 3.5 MiB
    bf16* Wq16 = (bf16*)(D);
    bf16* Wk16 = (bf16*)(D + 65536);
    bf16* Wv16 = (bf16*)(D + 131072);
    bf16* Wm16 = (bf16*)(D + 196608);
    bf16* W116 = (bf16*)(D + 262144);
    bf16* W216 = (bf16*)(D + 1310720);
    // d_out (33.55 MB) phased scratch:
    bf16* tgt16 = (bf16*)d_out;                       // [0, 16.78 MB)
    bf16* src16 = (bf16*)((char*)d_out + 16777216);   // [16.78, 33.55 MB)
    bf16* Pbuf  = (bf16*)d_out;                       // 16 windows bf16 P
    bf16* hid   = (bf16*)d_out;                       // MLP slab hidden

    // 0) weights + activations -> bf16
    cvtw_k<<<dim3(256, 6), 256, 0, stream>>>(Wq, Wk, Wv, Wm, W1, W2, D);
    cvt_k<<<4096, 256, 0, stream>>>(target, (unsigned short*)tgt16, 2097152);
    cvt_k<<<4096, 256, 0, stream>>>(source, (unsigned short*)src16, 2097152);

    // 1) projections (roll+window-permuted store) + V transpose
    gemm_bt<MODE_QKV, false><<<dim3(256, 2, 1), 256, 0, stream>>>(
        tgt16, nullptr, Wv16, RB, 256, 256, 0, 0, 0);
    transpose_vw<<<dim3(16, 4, 32), 256, 0, stream>>>(RB, RC);
    gemm_bt<MODE_QKV, false><<<dim3(256, 2, 1), 256, 0, stream>>>(
        tgt16, nullptr, Wk16, RB, 256, 256, 0, 0, 0);
    gemm_bt<MODE_QKV, false><<<dim3(256, 2, 1), 256, 0, stream>>>(
        src16, nullptr, Wq16, RA, 256, 256, 0, 0, 0);

    // 2) attention in two halves of 16 windows (P = full d_out as bf16)
    for (int h = 0; h < 2; ++h) {
        const long wo = (long)h * 16 * 262144;
        attn_sm<<<dim3(32, 16), 256, 0, stream>>>(
            RA + wo, RB + wo, mask, Pbuf, h * 16);
        gemm_bt<MODE_PV, false><<<dim3(8, 2, 16), 256, 0, stream>>>(
            Pbuf, nullptr, RC + wo, RA, 1024, 256, 1048576, 262144, h * 16);
    }

    // 3) msg @ Wm^T -> RB ; LN1 -> RC ; re-convert source -> RA
    gemm_bt<MODE_PLAIN, false><<<dim3(256, 2, 1), 256, 0, stream>>>(
        RA, nullptr, Wm16, RB, 256, 256, 0, 0, 0);
    ln1_k<<<8192, 256, 0, stream>>>(RB, ln1g, ln1b, RC);
    cvt_k<<<8192, 256, 0, stream>>>(source, (unsigned short*)RA, 2097152);

    // 4) MLP, 4 slabs of 8192 rows (hid = full d_out, out -> RB)
    for (int sl = 0; sl < 4; ++sl) {
        const long ro = (long)sl * 8192 * 256;
        gemm_bt<MODE_GELU, true><<<dim3(64, 16, 1), 256, 0, stream>>>(
            RA + ro, RC + ro, W116, hid, 512, 2048, 0, 0, 0);
        gemm_bt<MODE_PLAIN, false><<<dim3(64, 2, 1), 256, 0, stream>>>(
            hid, nullptr, W216, RB + ro, 2048, 256, 0, 0, 0);
    }

    // 5) LN2 + fp32 residual -> d_out
    ln2_k<<<8192, 256, 0, stream>>>(RB, ln2g, ln2b, source, out);
}

// Round 7
// 730.647 us; speedup vs baseline: 1.2660x; 1.0023x over previous
//
#include <hip/hip_runtime.h>
#include <hip/hip_bf16.h>

// TransformerLayer (Swin shifted-window attention + MLP), fp32 I/O, MI355X.
// R7: attn_sm two-pass K-staging (LDS 34.5KB) + launch_bounds(256,3) for
// 3 blocks/CU; mask converted to bf16 once; MLP1 fast GELU (tanh via expf).
// Phases:
//  0. cvtw weights+mask->D ; cvt target->d_out.lo ; cvt source->d_out.hi
//  1. vw=QKV(tgt,Wv)->RB ; vwT=transpose->RC ; kw=QKV(tgt,Wk)->RB ; qw=QKV(src,Wq)->RA
//  2. 2x half (16 win): attn_sm(qw,kw,mask16)->P=d_out ; PV(P,vwT)->msg (in RA)
//  3. msg@Wm^T->RB ; LN1->RC ; cvt source->RA(src16)
//  4. 4x slab: MLP1(src16|msg_ln,W1,gelu)->hid=d_out ; MLP2(hid,W2)->RB
//  5. LN2(RB)+source(fp32) -> d_out fp32

using bf16 = __hip_bfloat16;
typedef __attribute__((ext_vector_type(8))) short short8;
typedef __attribute__((ext_vector_type(4))) float f32x4;

__device__ __forceinline__ float bf2f(unsigned short b) {
    return __uint_as_float(((unsigned)b) << 16);
}
__device__ __forceinline__ unsigned short f2bf(float f) {
    unsigned u = __float_as_uint(f);
    unsigned r = (u + 0x7FFFu + ((u >> 16) & 1u)) >> 16;
    return (unsigned short)r;
}
__device__ __forceinline__ void cp16(const void* g, void* l) {
    __builtin_amdgcn_global_load_lds((const __attribute__((address_space(1))) void*)g,
                                     (__attribute__((address_space(3))) void*)l,
                                     16, 0, 0);
}
__device__ __forceinline__ float fast_gelu(float v) {
    // 0.5v(1+tanh(0.79788456(v+0.044715v^3))); tanh(z)=1-2/(exp(2z)+1)
    const float z = v * (0.7978845608028654f + 0.0356774081f * v * v);
    const float t = 1.f - 2.f / (__expf(2.f * z) + 1.f);
    return 0.5f * v * (1.f + t);
}

constexpr int MODE_PLAIN = 0;
constexpr int MODE_QKV   = 1;  // store bf16 at roll(-16)+window-permuted row
constexpr int MODE_PV    = 2;  // store bf16 at de-windowed + inverse-roll row
constexpr int MODE_GELU  = 3;  // fast gelu then bf16 store

// C[M,N] = A[M,K] @ B[N,K]^T ; bf16 operands, fp32 acc. m97 structure.
template<int MODE, bool CONCAT>
__global__ __launch_bounds__(256)
void gemm_bt(const bf16* __restrict__ A, const bf16* __restrict__ A2,
             const bf16* __restrict__ Bm, void* __restrict__ C,
             int K, int ldc, long sAz, long sBz, int wbase)
{
    __shared__ __align__(16) bf16 As[128 * 32];
    __shared__ __align__(16) bf16 Bs[128 * 32];

    const int z = blockIdx.z;
    A  += (long)z * sAz;
    Bm += (long)z * sBz;

    const int tid  = threadIdx.x;
    const int wave = tid >> 6, lane = tid & 63;
    const int wm = wave >> 1, wn = wave & 1;
    const int quad = lane >> 4, lrow = lane & 15;
    const int m0 = blockIdx.x * 128, n0 = blockIdx.y * 128;

    f32x4 acc[4][4];
#pragma unroll
    for (int i = 0; i < 4; i++)
#pragma unroll
        for (int j = 0; j < 4; j++) acc[i][j] = (f32x4){0.f, 0.f, 0.f, 0.f};

    for (int k0 = 0; k0 < K; k0 += 32) {
#pragma unroll
        for (int inst = 0; inst < 2; ++inst) {
            const int chunk = wave * 2 + inst;
            const int u   = chunk * 64 + lane;
            const int row = u >> 2;
            const int kk  = (u & 3) << 3;
            const bf16* ga;
            if (CONCAT) {
                ga = (k0 < 256) ? (A  + (long)(m0 + row) * 256 + (k0 + kk))
                                : (A2 + (long)(m0 + row) * 256 + (k0 - 256 + kk));
            } else {
                ga = A + (long)(m0 + row) * K + (k0 + kk);
            }
            cp16(ga, As + chunk * 512);
            const bf16* gb = Bm + (long)(n0 + row) * K + (k0 + kk);
            cp16(gb, Bs + chunk * 512);
        }
        __syncthreads();

        short8 af[4], bfv[4];
#pragma unroll
        for (int i = 0; i < 4; i++) {
            af[i]  = *(const short8*)(As + (wm * 64 + i * 16 + lrow) * 32 + quad * 8);
            bfv[i] = *(const short8*)(Bs + (wn * 64 + i * 16 + lrow) * 32 + quad * 8);
        }
#pragma unroll
        for (int i = 0; i < 4; i++)
#pragma unroll
            for (int j = 0; j < 4; j++)
                acc[i][j] = __builtin_amdgcn_mfma_f32_16x16x32_bf16(
                    af[i], bfv[j], acc[i][j], 0, 0, 0);
        __syncthreads();
    }

    // C/D layout: col = lane&15, row = quad*4 + reg (m89/m91 verified)
    unsigned short* outb = (unsigned short*)C;
    if (MODE == MODE_PV) {
        const int win = wbase + z;
        const int batch = win >> 2;
        const int s1 = (win >> 1) & 1, s2 = win & 1;
#pragma unroll
        for (int i = 0; i < 4; i++)
#pragma unroll
            for (int j = 0; j < 4; j++)
#pragma unroll
                for (int r = 0; r < 4; r++) {
                    const int gm = m0 + wm * 64 + i * 16 + quad * 4 + r;
                    const int gn = n0 + wn * 64 + j * 16 + lrow;
                    const int r5 = gm >> 5, c5 = gm & 31;
                    const int ii = ((s1 << 5) + r5 + 16) & 63;   // inverse roll
                    const int jj = ((s2 << 5) + c5 + 16) & 63;
                    const long mr = (long)batch * 4096 + ii * 64 + jj;
                    outb[mr * 256 + gn] = f2bf(acc[i][j][r]);
                }
    } else if (MODE == MODE_QKV) {
#pragma unroll
        for (int i = 0; i < 4; i++)
#pragma unroll
            for (int j = 0; j < 4; j++)
#pragma unroll
                for (int r = 0; r < 4; r++) {
                    const int gm = m0 + wm * 64 + i * 16 + quad * 4 + r;
                    const int gn = n0 + wn * 64 + j * 16 + lrow;
                    const int batch = gm >> 12, pos = gm & 4095;
                    const int ii = pos >> 6, jj = pos & 63;
                    const int ri = (ii + 48) & 63, rj = (jj + 48) & 63; // roll(-16)
                    const long prow =
                        ((long)((batch << 2) + ((ri >> 5) << 1) + (rj >> 5)) << 10)
                        + ((ri & 31) << 5) + (rj & 31);
                    outb[prow * 256 + gn] = f2bf(acc[i][j][r]);
                }
    } else {
#pragma unroll
        for (int i = 0; i < 4; i++)
#pragma unroll
            for (int j = 0; j < 4; j++)
#pragma unroll
                for (int r = 0; r < 4; r++) {
                    const int gm = m0 + wm * 64 + i * 16 + quad * 4 + r;
                    const int gn = n0 + wn * 64 + j * 16 + lrow;
                    float v = acc[i][j][r];
                    if (MODE == MODE_GELU) v = fast_gelu(v);
                    outb[(long)gm * ldc + gn] = f2bf(v);
                }
    }
}

// Fused score+softmax: one block = 32 Q-rows x full 1024 K-cols of one window.
// Two-pass K staging (512 keys/pass) -> LDS 34.5 KB; launch_bounds(256,3)
// targets 3 blocks/CU (round-6 was 2, VGPR/LDS-clamped, Occupancy 10%).
__global__ __launch_bounds__(256, 3)
void attn_sm(const bf16* __restrict__ Q, const bf16* __restrict__ Kw,
             const bf16* __restrict__ mask16, bf16* __restrict__ P, int wbase)
{
    __shared__ __align__(16) bf16 Ks[512 * 32];    // 32 KB
    __shared__ __align__(16) bf16 Qs[32 * 32];     // 2 KB
    __shared__ float redm[2][2][16], redl[2][2][16];

    const int win = blockIdx.y;
    const long wo = (long)win << 18;
    const bf16* Qp = Q + wo;
    const bf16* Kp = Kw + wo;
    unsigned short* Pp = (unsigned short*)P + ((long)win << 20);
    const unsigned short* mk =
        (const unsigned short*)mask16 + (((long)((wbase + win) & 3)) << 20);

    const int tid = threadIdx.x;
    const int wave = tid >> 6, lane = tid & 63;
    const int wm = wave >> 1, wn = wave & 1;
    const int quad = lane >> 4, lrow = lane & 15;
    const int m0 = blockIdx.x * 32;

    f32x4 acc[32];
#pragma unroll
    for (int t = 0; t < 32; t++) acc[t] = (f32x4){0.f, 0.f, 0.f, 0.f};

    for (int h = 0; h < 2; ++h) {
        for (int k0 = 0; k0 < 256; k0 += 32) {
            if (wave < 2) {  // Q-tile 32x32
                const int u = wave * 64 + lane;
                const int row = u >> 2, kk = (u & 3) << 3;
                cp16(Qp + (long)(m0 + row) * 256 + k0 + kk, Qs + u * 8);
            }
#pragma unroll
            for (int i = 0; i < 8; ++i) {   // K-tile 512x32
                const int c = wave * 8 + i;              // key-frag 0..31
                const int u = c * 64 + lane;
                const int row = u >> 2, kk = (u & 3) << 3;  // row 0..511
                cp16(Kp + (long)(h * 512 + row) * 256 + k0 + kk, Ks + u * 8);
            }
            __syncthreads();
            const short8 af = *(const short8*)(Qs + (wm * 16 + lrow) * 32 + quad * 8);
#pragma unroll
            for (int t = 0; t < 16; ++t) {
                const short8 bfv =
                    *(const short8*)(Ks + (wn * 256 + t * 16 + lrow) * 32 + quad * 8);
                acc[h * 16 + t] =
                    __builtin_amdgcn_mfma_f32_16x16x32_bf16(af, bfv, acc[h * 16 + t], 0, 0, 0);
            }
            __syncthreads();
        }
    }

    // cols: gc = (a>>4)*512 + wn*256 + (a&15)*16 + lrow ; rows rowb..rowb+3
    const int rowb = m0 + wm * 16 + quad * 4;
    for (int a = 0; a < 32; ++a) {
        const int gc = ((a >> 4) << 9) + (wn << 8) + ((a & 15) << 4) + lrow;
#pragma unroll
        for (int r = 0; r < 4; ++r)
            acc[a][r] = acc[a][r] * 0.0625f + bf2f(mk[(long)(rowb + r) << 10 | gc]);
    }

    float m_[4], fac[4];
#pragma unroll
    for (int r = 0; r < 4; ++r) {
        float mx = -3.4e38f;
        for (int a = 0; a < 32; ++a) mx = fmaxf(mx, acc[a][r]);
#pragma unroll
        for (int o = 1; o < 16; o <<= 1) mx = fmaxf(mx, __shfl_xor(mx, o, 64));
        m_[r] = mx;
        float s = 0.f;
        for (int a = 0; a < 32; ++a) { const float e = __expf(acc[a][r] - mx); acc[a][r] = e; s += e; }
#pragma unroll
        for (int o = 1; o < 16; o <<= 1) s += __shfl_xor(s, o, 64);
        fac[r] = s;
    }
    if (lrow == 0) {
#pragma unroll
        for (int r = 0; r < 4; ++r) {
            redm[wm][wn][quad * 4 + r] = m_[r];
            redl[wm][wn][quad * 4 + r] = fac[r];
        }
    }
    __syncthreads();
#pragma unroll
    for (int r = 0; r < 4; ++r) {
        const int ri = quad * 4 + r;
        const float ma = redm[wm][0][ri], mb = redm[wm][1][ri];
        const float M = fmaxf(ma, mb);
        const float L = redl[wm][0][ri] * __expf(ma - M) + redl[wm][1][ri] * __expf(mb - M);
        fac[r] = __expf(m_[r] - M) / L;
    }
    for (int a = 0; a < 32; ++a) {
        const int gc = ((a >> 4) << 9) + (wn << 8) + ((a & 15) << 4) + lrow;
#pragma unroll
        for (int r = 0; r < 4; ++r)
            Pp[(long)(rowb + r) << 10 | gc] = f2bf(acc[a][r] * fac[r]);
    }
}

// merged conversion: 6 weights + mask, segments by blockIdx.y
__global__ __launch_bounds__(256)
void cvtw_k(const float* __restrict__ w0, const float* __restrict__ w1,
            const float* __restrict__ w2, const float* __restrict__ w3,
            const float* __restrict__ w4, const float* __restrict__ w5,
            const float* __restrict__ w6, unsigned short* __restrict__ d)
{
    const float* s; long n4, off4;
    switch (blockIdx.y) {
    case 0:  s = w0; n4 = 16384;   off4 = 0;      break;
    case 1:  s = w1; n4 = 16384;   off4 = 16384;  break;
    case 2:  s = w2; n4 = 16384;   off4 = 32768;  break;
    case 3:  s = w3; n4 = 16384;   off4 = 49152;  break;
    case 4:  s = w4; n4 = 262144;  off4 = 65536;  break;
    case 5:  s = w5; n4 = 131072;  off4 = 327680; break;
    default: s = w6; n4 = 1048576; off4 = 458752; break;  // mask
    }
    ushort4* dst = (ushort4*)d + off4;
    for (long i = (long)blockIdx.x * 256 + threadIdx.x; i < n4;
         i += (long)gridDim.x * 256) {
        const float4 v = ((const float4*)s)[i];
        ushort4 o;
        o.x = f2bf(v.x); o.y = f2bf(v.y); o.z = f2bf(v.z); o.w = f2bf(v.w);
        dst[i] = o;
    }
}

__global__ __launch_bounds__(256)
void cvt_k(const float* __restrict__ s, unsigned short* __restrict__ d, long n4)
{
    for (long i = (long)blockIdx.x * 256 + threadIdx.x; i < n4;
         i += (long)gridDim.x * 256) {
        const float4 v = ((const float4*)s)[i];
        ushort4 o;
        o.x = f2bf(v.x); o.y = f2bf(v.y); o.z = f2bf(v.z); o.w = f2bf(v.w);
        ((ushort4*)d)[i] = o;
    }
}

// vwT[win][c][s] = vw[win][s][c], 64x64 LDS tiles
__global__ __launch_bounds__(256)
void transpose_vw(const bf16* __restrict__ vw, bf16* __restrict__ vwT)
{
    __shared__ bf16 t[64][65];
    const int win = blockIdx.z;
    const int s0 = blockIdx.x * 64, c0 = blockIdx.y * 64;
    const bf16* src = vw  + ((long)win << 18);
    bf16*       dst = vwT + ((long)win << 18);
    const int tid = threadIdx.x;
#pragma unroll
    for (int ii = 0; ii < 16; ++ii) {
        const int lin = ii * 256 + tid;
        const int r = lin >> 6, c = lin & 63;
        t[r][c] = src[(long)(s0 + r) * 256 + c0 + c];
    }
    __syncthreads();
#pragma unroll
    for (int ii = 0; ii < 16; ++ii) {
        const int lin = ii * 256 + tid;
        const int r = lin >> 6, c = lin & 63;
        dst[(long)(c0 + r) * 1024 + s0 + c] = t[c][r];
    }
}

// LN1: bf16 in -> bf16 out, fp32 gamma/beta. One 256-ch row per wave.
__global__ __launch_bounds__(256)
void ln1_k(const bf16* __restrict__ x, const float* __restrict__ g,
           const float* __restrict__ be, bf16* __restrict__ out)
{
    const int wave = threadIdx.x >> 6, lane = threadIdx.x & 63;
    const long row = (long)blockIdx.x * 4 + wave;
    const ushort4 u = ((const ushort4*)((const unsigned short*)x + (row << 8)))[lane];
    const float v0 = bf2f(u.x), v1 = bf2f(u.y), v2 = bf2f(u.z), v3 = bf2f(u.w);
    float s = v0 + v1 + v2 + v3;
    float q = v0 * v0 + v1 * v1 + v2 * v2 + v3 * v3;
#pragma unroll
    for (int o = 1; o < 64; o <<= 1) { s += __shfl_xor(s, o, 64); q += __shfl_xor(q, o, 64); }
    const float mean = s * 0.00390625f;
    const float var  = q * 0.00390625f - mean * mean;
    const float inv  = rsqrtf(fmaxf(var, 0.f) + 1e-5f);
    const float4 gg = ((const float4*)g)[lane];
    const float4 bb = ((const float4*)be)[lane];
    ushort4 o4;
    o4.x = f2bf((v0 - mean) * inv * gg.x + bb.x);
    o4.y = f2bf((v1 - mean) * inv * gg.y + bb.y);
    o4.z = f2bf((v2 - mean) * inv * gg.z + bb.z);
    o4.w = f2bf((v3 - mean) * inv * gg.w + bb.w);
    ((ushort4*)((unsigned short*)out + (row << 8)))[lane] = o4;
}

// LN2 + residual: bf16 in, fp32 gamma/beta/residual, fp32 out.
__global__ __launch_bounds__(256)
void ln2_k(const bf16* __restrict__ x, const float* __restrict__ g,
           const float* __restrict__ be, const float* __restrict__ res,
           float* __restrict__ out)
{
    const int wave = threadIdx.x >> 6, lane = threadIdx.x & 63;
    const long row = (long)blockIdx.x * 4 + wave;
    const ushort4 u = ((const ushort4*)((const unsigned short*)x + (row << 8)))[lane];
    const float v0 = bf2f(u.x), v1 = bf2f(u.y), v2 = bf2f(u.z), v3 = bf2f(u.w);
    float s = v0 + v1 + v2 + v3;
    float q = v0 * v0 + v1 * v1 + v2 * v2 + v3 * v3;
#pragma unroll
    for (int o = 1; o < 64; o <<= 1) { s += __shfl_xor(s, o, 64); q += __shfl_xor(q, o, 64); }
    const float mean = s * 0.00390625f;
    const float var  = q * 0.00390625f - mean * mean;
    const float inv  = rsqrtf(fmaxf(var, 0.f) + 1e-5f);
    const float4 gg = ((const float4*)g)[lane];
    const float4 bb = ((const float4*)be)[lane];
    const float4 rr = ((const float4*)(res + (row << 8)))[lane];
    float4 o4;
    o4.x = (v0 - mean) * inv * gg.x + bb.x + rr.x;
    o4.y = (v1 - mean) * inv * gg.y + bb.y + rr.y;
    o4.z = (v2 - mean) * inv * gg.z + bb.z + rr.z;
    o4.w = (v3 - mean) * inv * gg.w + bb.w + rr.w;
    ((float4*)(out + (row << 8)))[lane] = o4;
}

extern "C" void kernel_launch(void* const* d_in, const int* in_sizes, int n_in,
                              void* d_out, int out_size, void* d_ws, size_t ws_size,
                              hipStream_t stream)
{
    const float* source = (const float*)d_in[0];
    const float* target = (const float*)d_in[1];
    const float* mask   = (const float*)d_in[2];
    const float* Wq = (const float*)d_in[3];
    const float* Wk = (const float*)d_in[4];
    const float* Wv = (const float*)d_in[5];
    const float* Wm = (const float*)d_in[6];
    const float* ln1g = (const float*)d_in[7];
    const float* ln1b = (const float*)d_in[8];
    const float* W1 = (const float*)d_in[9];
    const float* W2 = (const float*)d_in[10];
    const float* ln2g = (const float*)d_in[11];
    const float* ln2b = (const float*)d_in[12];
    float* out = (float*)d_out;

    char* ws = (char*)d_ws;
    const size_t MB = 1ull << 20;

    bf16* RA = (bf16*)(ws +  0 * MB);   // qw -> msg -> src16
    bf16* RB = (bf16*)(ws + 16 * MB);   // vw -> kw -> msg_mm -> mlp_out
    bf16* RC = (bf16*)(ws + 32 * MB);   // vwT -> msg_ln
    unsigned short* D = (unsigned short*)(ws + 48 * MB);  // weights+mask bf16, 11.9 MiB
    bf16* Wq16 = (bf16*)(D);
    bf16* Wk16 = (bf16*)(D + 65536);
    bf16* Wv16 = (bf16*)(D + 131072);
    bf16* Wm16 = (bf16*)(D + 196608);
    bf16* W116 = (bf16*)(D + 262144);
    bf16* W216 = (bf16*)(D + 1310720);
    bf16* mask16 = (bf16*)(D + 1835008);
    // d_out (33.55 MB) phased scratch:
    bf16* tgt16 = (bf16*)d_out;                       // [0, 16.78 MB)
    bf16* src16 = (bf16*)((char*)d_out + 16777216);   // [16.78, 33.55 MB)
    bf16* Pbuf  = (bf16*)d_out;                       // 16 windows bf16 P
    bf16* hid   = (bf16*)d_out;                       // MLP slab hidden

    // 0) weights + mask + activations -> bf16
    cvtw_k<<<dim3(256, 7), 256, 0, stream>>>(Wq, Wk, Wv, Wm, W1, W2, mask, D);
    cvt_k<<<4096, 256, 0, stream>>>(target, (unsigned short*)tgt16, 2097152);
    cvt_k<<<4096, 256, 0, stream>>>(source, (unsigned short*)src16, 2097152);

    // 1) projections (roll+window-permuted store) + V transpose
    gemm_bt<MODE_QKV, false><<<dim3(256, 2, 1), 256, 0, stream>>>(
        tgt16, nullptr, Wv16, RB, 256, 256, 0, 0, 0);
    transpose_vw<<<dim3(16, 4, 32), 256, 0, stream>>>(RB, RC);
    gemm_bt<MODE_QKV, false><<<dim3(256, 2, 1), 256, 0, stream>>>(
        tgt16, nullptr, Wk16, RB, 256, 256, 0, 0, 0);
    gemm_bt<MODE_QKV, false><<<dim3(256, 2, 1), 256, 0, stream>>>(
        src16, nullptr, Wq16, RA, 256, 256, 0, 0, 0);

    // 2) attention in two halves of 16 windows (P = full d_out as bf16)
    for (int h = 0; h < 2; ++h) {
        const long wo = (long)h * 16 * 262144;
        attn_sm<<<dim3(32, 16), 256, 0, stream>>>(
            RA + wo, RB + wo, mask16, Pbuf, h * 16);
        gemm_bt<MODE_PV, false><<<dim3(8, 2, 16), 256, 0, stream>>>(
            Pbuf, nullptr, RC + wo, RA, 1024, 256, 1048576, 262144, h * 16);
    }

    // 3) msg @ Wm^T -> RB ; LN1 -> RC ; re-convert source -> RA
    gemm_bt<MODE_PLAIN, false><<<dim3(256, 2, 1), 256, 0, stream>>>(
        RA, nullptr, Wm16, RB, 256, 256, 0, 0, 0);
    ln1_k<<<8192, 256, 0, stream>>>(RB, ln1g, ln1b, RC);
    cvt_k<<<8192, 256, 0, stream>>>(source, (unsigned short*)RA, 2097152);

    // 4) MLP, 4 slabs of 8192 rows (hid = full d_out, out -> RB)
    for (int sl = 0; sl < 4; ++sl) {
        const long ro = (long)sl * 8192 * 256;
        gemm_bt<MODE_GELU, true><<<dim3(64, 16, 1), 256, 0, stream>>>(
            RA + ro, RC + ro, W116, hid, 512, 2048, 0, 0, 0);
        gemm_bt<MODE_PLAIN, false><<<dim3(64, 2, 1), 256, 0, stream>>>(
            hid, nullptr, W216, RB + ro, 2048, 256, 0, 0, 0);
    }

    // 5) LN2 + fp32 residual -> d_out
    ln2_k<<<8192, 256, 0, stream>>>(RB, ln2g, ln2b, source, out);
}